// Round 6
// baseline (3352.934 us; speedup 1.0000x reference)
//
#include <hip/hip_runtime.h>
#include <math.h>

#define EPS_MODE 0

typedef unsigned short u16;
typedef short bf16x8 __attribute__((ext_vector_type(8)));
typedef float f32x4 __attribute__((ext_vector_type(4)));
typedef u16 u16x4 __attribute__((ext_vector_type(4)));
typedef u16 u16x8 __attribute__((ext_vector_type(8)));

static constexpr int T = 16;
static constexpr size_t MF = 1u << 20;
static constexpr int DKCH = 256;                // dense split-K chunks
static constexpr int DKCHUNK = 196608 / DKCH;   // 768

__device__ __forceinline__ u16 f2bf(float f) {
  unsigned u = __float_as_uint(f);
  unsigned r = (u + 0x7fffu + ((u >> 16) & 1u)) >> 16;
  return (u16)r;
}
__device__ __forceinline__ float bf2f(u16 h) {
  return __uint_as_float(((unsigned)h) << 16);
}
__device__ __forceinline__ void gload16(const void* g, void* l) {
  __builtin_amdgcn_global_load_lds(
      (const __attribute__((address_space(1))) void*)g,
      (__attribute__((address_space(3))) void*)l, 16, 0, 0);
}
__device__ __forceinline__ float sigm(float x) { return 1.f / (1.f + expf(-x)); }

// ---------------- casts -------------------------------------------------------------
__global__ __launch_bounds__(256) void cast_bf16(const float* __restrict__ in,
                                                 u16* __restrict__ out, int n) {
  int i = (blockIdx.x * 256 + threadIdx.x) * 4;
  if (i < n) {
    float4 v = *reinterpret_cast<const float4*>(&in[i]);
    out[i + 0] = f2bf(v.x); out[i + 1] = f2bf(v.y);
    out[i + 2] = f2bf(v.z); out[i + 3] = f2bf(v.w);
  }
}

// ---------------- W transpose+cast: WT[col][k] --------------------------------------
__global__ __launch_bounds__(256) void prep_wt(const float* __restrict__ Wz0, const float* __restrict__ Wr0,
                                               const float* __restrict__ Wn0, const float* __restrict__ Wz1,
                                               const float* __restrict__ Wr1, const float* __restrict__ Wn1,
                                               u16* __restrict__ WzrT0, u16* __restrict__ WnT0,
                                               u16* __restrict__ WzrT1, u16* __restrict__ WnT1) {
  int seg = blockIdx.y;
  int idx = blockIdx.x * 256 + threadIdx.x;
  if (seg == 0) {        // [128 out][64 k] : z|r, h-part rows 1..64
    if (idx < 128 * 64) {
      int j = idx >> 6, k = idx & 63;
      float v = (j < 64) ? Wz0[(k + 1) * 64 + j] : Wr0[(k + 1) * 64 + (j - 64)];
      WzrT0[idx] = f2bf(v);
    }
  } else if (seg == 1) {  // [64][64]
    if (idx < 64 * 64) {
      int j = idx >> 6, k = idx & 63;
      WnT0[idx] = f2bf(Wn0[(k + 1) * 64 + j]);
    }
  } else if (seg == 2) {  // [256 out][192 k]
    if (idx < 256 * 192) {
      int j = idx / 192, k = idx % 192;
      float v = (j < 128) ? Wz1[k * 128 + j] : Wr1[k * 128 + (j - 128)];
      WzrT1[idx] = f2bf(v);
    }
  } else {                // [128][192]
    if (idx < 128 * 192) {
      int j = idx / 192, k = idx % 192;
      WnT1[idx] = f2bf(Wn1[k * 128 + j]);
    }
  }
}

// ---------------- adjacency MFMA GEMM (device, EPI1 = AX f32 out) -------------------
template <int EPI, int LOGC, int MFR>
__device__ __forceinline__ void dev_adj_mfma(int bx, int by, char* lds,
                                             const u16* __restrict__ A,
                                             const u16* __restrict__ BT,
                                             void* __restrict__ OUT) {
  constexpr int MT = MFR * 32;
  int tid = threadIdx.x;
  int w = tid >> 6, lane = tid & 63;
  int row0 = by * MT, col0 = bx * 128;
  int wm = w >> 1, wn = w & 1;
  f32x4 acc[MFR][4] = {};
  for (int k0 = 0; k0 < 1024; k0 += 64) {
#pragma unroll
    for (int q = 0; q < MFR; ++q) {
      int row = q * 32 + w * 8 + (lane >> 3);
      gload16(A + (size_t)(row0 + row) * 1024 + k0 + (lane & 7) * 8,
              lds + q * 4096 + w * 1024);
    }
#pragma unroll
    for (int q = 0; q < 4; ++q) {
      int row = q * 32 + w * 8 + (lane >> 3);
      gload16(BT + (size_t)(col0 + row) * 1024 + k0 + (lane & 7) * 8,
              lds + MFR * 4096 + q * 4096 + w * 1024);
    }
    __syncthreads();
#pragma unroll
    for (int kk = 0; kk < 2; ++kk) {
      bf16x8 a[MFR], bb[4];
#pragma unroll
      for (int m = 0; m < MFR; ++m)
        a[m] = *(const bf16x8*)(lds + (wm * (MFR * 16) + m * 16 + (lane & 15)) * 128 + kk * 64 + (lane >> 4) * 16);
#pragma unroll
      for (int n = 0; n < 4; ++n)
        bb[n] = *(const bf16x8*)(lds + MFR * 4096 + (wn * 64 + n * 16 + (lane & 15)) * 128 + kk * 64 + (lane >> 4) * 16);
#pragma unroll
      for (int m = 0; m < MFR; ++m)
#pragma unroll
        for (int n = 0; n < 4; ++n)
          acc[m][n] = __builtin_amdgcn_mfma_f32_16x16x32_bf16(a[m], bb[n], acc[m][n], 0, 0, 0);
    }
    __syncthreads();
  }
  if (EPI == 1) {
    float* O = (float*)OUT;
#pragma unroll
    for (int m = 0; m < MFR; ++m)
#pragma unroll
      for (int n = 0; n < 4; ++n) {
        int col = col0 + wn * 64 + n * 16 + (lane & 15);
        int t = col >> 6, bbx = col & 63;
        int row = row0 + wm * (MFR * 16) + m * 16 + ((lane >> 4) << 2);
        *(float4*)&O[((size_t)t << 16) + ((size_t)bbx << 10) + row] = *(float4*)&acc[m][n];
      }
  } else {
    u16* O = (u16*)OUT;
    constexpr int C = 1 << LOGC;
#pragma unroll
    for (int m = 0; m < MFR; ++m)
#pragma unroll
      for (int n = 0; n < 4; ++n) {
        int col = col0 + wn * 64 + n * 16 + (lane & 15);
        int bbx = col >> LOGC, c = col & (C - 1);
#pragma unroll
        for (int j = 0; j < 4; ++j) {
          int row = row0 + wm * (MFR * 16) + m * 16 + ((lane >> 4) << 2) + j;
          O[(((size_t)bbx << 10) + row) * C + c] = f2bf(acc[m][n][j]);
        }
      }
  }
}

template <int EPI, int LOGC, int MFR>
__global__ __launch_bounds__(256) void adj_mfma(const u16* __restrict__ A,
                                                const u16* __restrict__ BT,
                                                void* __restrict__ OUT) {
  __shared__ __align__(16) char lds[(MFR + 4) * 4096];
  dev_adj_mfma<EPI, LOGC, MFR>(blockIdx.x, blockIdx.y, lds, A, BT, OUT);
}

// ---------------- fused adj@(r*h) + n-gate + GRU update (device) --------------------
template <int C, int RK1, int MFR>
__device__ __forceinline__ void dev_adj_ngate(
    int bx, int by, char* lds,
    const u16* __restrict__ A, const u16* __restrict__ BT,
    const u16* __restrict__ WnT, const float* __restrict__ bias,
    const float* __restrict__ axv, const float* __restrict__ wx,
    const u16* __restrict__ AH1, const u16* __restrict__ zT,
    u16* __restrict__ hT) {
  constexpr int LOGC = (C == 64) ? 6 : 7;
  constexpr int KW = (C == 64) ? 64 : 192;
  constexpr int KKAN = C / 32;
  constexpr int MT = MFR * 32;
  int tid = threadIdx.x;
  int w = tid >> 6, lane = tid & 63;
  int row0 = by * MT, col0 = bx * 128;
  int wm = w >> 1, wn = w & 1;
  f32x4 acc[MFR][4] = {};
  for (int k0 = 0; k0 < 1024; k0 += 64) {
#pragma unroll
    for (int q = 0; q < MFR; ++q) {
      int row = q * 32 + w * 8 + (lane >> 3);
      gload16(A + (size_t)(row0 + row) * 1024 + k0 + (lane & 7) * 8,
              lds + q * 4096 + w * 1024);
    }
#pragma unroll
    for (int q = 0; q < 4; ++q) {
      int row = q * 32 + w * 8 + (lane >> 3);
      gload16(BT + (size_t)(col0 + row) * 1024 + k0 + (lane & 7) * 8,
              lds + MFR * 4096 + q * 4096 + w * 1024);
    }
    __syncthreads();
#pragma unroll
    for (int kk = 0; kk < 2; ++kk) {
      bf16x8 a[MFR], bb[4];
#pragma unroll
      for (int m = 0; m < MFR; ++m)
        a[m] = *(const bf16x8*)(lds + (wm * (MFR * 16) + m * 16 + (lane & 15)) * 128 + kk * 64 + (lane >> 4) * 16);
#pragma unroll
      for (int n = 0; n < 4; ++n)
        bb[n] = *(const bf16x8*)(lds + MFR * 4096 + (wn * 64 + n * 16 + (lane & 15)) * 128 + kk * 64 + (lane >> 4) * 16);
#pragma unroll
      for (int m = 0; m < MFR; ++m)
#pragma unroll
        for (int n = 0; n < 4; ++n)
          acc[m][n] = __builtin_amdgcn_mfma_f32_16x16x32_bf16(a[m], bb[n], acc[m][n], 0, 0, 0);
    }
    __syncthreads();
  }
  u16* ANt = (u16*)lds;
#pragma unroll
  for (int m = 0; m < MFR; ++m)
#pragma unroll
    for (int n = 0; n < 4; ++n) {
      int cl = wn * 64 + n * 16 + (lane & 15);
      int rl = wm * (MFR * 16) + m * 16 + ((lane >> 4) << 2);
#pragma unroll
      for (int j = 0; j < 4; ++j)
        ANt[(rl + j) * 136 + cl] = f2bf(acc[m][n][j]);
    }
  __syncthreads();
  int wrow = w >> 1, half = w & 1;
  int arow0 = wrow * (MFR * 16);
  int b0 = col0 >> LOGC;
  int out0 = (C == 64) ? 0 : half * 64;
  int kbase = (C == 64) ? half * 64 : 0;
  int b_eff = (C == 64) ? (b0 + half) : b0;
  constexpr int WOFF = (C == 64) ? 0 : 64;
  f32x4 acc2[MFR][4] = {};
#pragma unroll
  for (int kk = 0; kk < KKAN; ++kk) {
    bf16x8 a[MFR], bb[4];
    int ka = kbase + kk * 32 + (lane >> 4) * 8;
#pragma unroll
    for (int m = 0; m < MFR; ++m)
      a[m] = *(const bf16x8*)&ANt[(arow0 + m * 16 + (lane & 15)) * 136 + ka];
#pragma unroll
    for (int n = 0; n < 4; ++n)
      bb[n] = *(const bf16x8*)&WnT[(size_t)(out0 + n * 16 + (lane & 15)) * KW + WOFF + kk * 32 + (lane >> 4) * 8];
#pragma unroll
    for (int m = 0; m < MFR; ++m)
#pragma unroll
      for (int n = 0; n < 4; ++n)
        acc2[m][n] = __builtin_amdgcn_mfma_f32_16x16x32_bf16(a[m], bb[n], acc2[m][n], 0, 0, 0);
  }
  if (C == 128) {  // + AH1 (x) part, K=64
#pragma unroll
    for (int kk = 0; kk < 2; ++kk) {
      bf16x8 a[MFR], bb[4];
#pragma unroll
      for (int m = 0; m < MFR; ++m)
        a[m] = *(const bf16x8*)&AH1[(((size_t)b0 << 10) + row0 + arow0 + m * 16 + (lane & 15)) * 64 + kk * 32 + (lane >> 4) * 8];
#pragma unroll
      for (int n = 0; n < 4; ++n)
        bb[n] = *(const bf16x8*)&WnT[(size_t)(out0 + n * 16 + (lane & 15)) * 192 + kk * 32 + (lane >> 4) * 8];
#pragma unroll
      for (int m = 0; m < MFR; ++m)
#pragma unroll
        for (int n = 0; n < 4; ++n)
          acc2[m][n] = __builtin_amdgcn_mfma_f32_16x16x32_bf16(a[m], bb[n], acc2[m][n], 0, 0, 0);
    }
  }
#pragma unroll
  for (int m = 0; m < MFR; ++m) {
    float ax4[4];
    if (RK1) {
      float4 v = *(const float4*)&axv[((size_t)b_eff << 10) + row0 + arow0 + m * 16 + ((lane >> 4) << 2)];
      ax4[0] = v.x; ax4[1] = v.y; ax4[2] = v.z; ax4[3] = v.w;
    }
#pragma unroll
    for (int n = 0; n < 4; ++n) {
      int cp = out0 + n * 16 + (lane & 15);
      int grow = arow0 + m * 16 + ((lane >> 4) << 2);
      size_t idx = (((size_t)b_eff << LOGC) + cp) * 1024 + row0 + grow;
      u16x4 zv = *(const u16x4*)&zT[idx];
      u16x4 hv = *(const u16x4*)&hT[idx];
      u16x4 pk;
#pragma unroll
      for (int j = 0; j < 4; ++j) {
        float g = acc2[m][n][j] + bias[cp];
        if (RK1) g += ax4[j] * wx[cp];
        float nv = tanhf(g);
        float z = bf2f(zv[j]), ho = bf2f(hv[j]);
        pk[j] = f2bf((1.f - z) * ho + z * nv);
      }
      *(u16x4*)&hT[idx] = pk;
    }
  }
}

template <int C, int RK1, int MFR>
__global__ __launch_bounds__(256) void adj_ngate(
    const u16* __restrict__ A, const u16* __restrict__ BT,
    const u16* __restrict__ WnT, const float* __restrict__ bias,
    const float* __restrict__ axv, const float* __restrict__ wx,
    const u16* __restrict__ AH1, const u16* __restrict__ zT,
    u16* __restrict__ hT) {
  constexpr int MT = MFR * 32;
  constexpr int STG = (MFR + 4) * 4096;
  constexpr int ANB = MT * 136 * 2;
  constexpr int LDSZ = STG > ANB ? STG : ANB;
  __shared__ __align__(16) char lds[LDSZ];
  dev_adj_ngate<C, RK1, MFR>(blockIdx.x, blockIdx.y, lds, A, BT, WnT, bias, axv, wx,
                             AH1, zT, hT);
}

// combo_ngate: blocks [0,512) = ngate128 (h2); [512,768) = ngate64 (h1, step+1 gates)
__global__ __launch_bounds__(256) void combo_ngate(
    const u16* __restrict__ adjB,
    const u16* __restrict__ rh1T, const u16* __restrict__ WnT1, const float* __restrict__ bn1,
    const u16* __restrict__ AH1, const u16* __restrict__ z1T, u16* __restrict__ h2T,
    const u16* __restrict__ rh0T, const u16* __restrict__ WnT0, const float* __restrict__ bn0,
    const float* __restrict__ AXt1, const float* __restrict__ Wn0,
    const u16* __restrict__ z0T, u16* __restrict__ h1T) {
  __shared__ __align__(16) char lds[34816];
  int bid = blockIdx.x;
  if (bid < 512)
    dev_adj_ngate<128, 0, 4>(bid & 63, bid >> 6, lds, adjB, rh1T, WnT1, bn1,
                             nullptr, nullptr, AH1, z1T, h2T);
  else {
    int b2 = bid - 512;
    dev_adj_ngate<64, 1, 4>(b2 & 31, b2 >> 5, lds, adjB, rh0T, WnT0, bn0,
                            AXt1, Wn0, nullptr, z0T, h1T);
  }
}

// ---------------- zr gate GEMM (prologue only) --------------------------------------
template <int WM, int WN, int C, int NK1, int NK, int RK1>
__global__ __launch_bounds__(256) void gate_zr(
    const u16* __restrict__ A1, const u16* __restrict__ A2,
    const u16* __restrict__ WT, const float* __restrict__ bz,
    const float* __restrict__ br, const float* __restrict__ axv,
    const float* __restrict__ wxz, const float* __restrict__ wxr,
    const u16* __restrict__ hT, u16* __restrict__ zTo, u16* __restrict__ rhTo) {
  constexpr int MT = WM * 64, NT = WN * 64, K = NK * 64;
  constexpr int NB = 1024 / MT;
  __shared__ __align__(16) char lds[MT * 128 + NT * 128];
  int tid = threadIdx.x;
  int w = tid >> 6, lane = tid & 63;
  int by = blockIdx.x;
  int b = by / NB, n0 = (by % NB) * MT;
  size_t row0 = ((size_t)b << 10) + n0;
  int wm = w / WN, wn = w % WN;
  f32x4 acc[4][4] = {};
  for (int s = 0; s < NK; ++s) {
    const u16* As; int astr, koff;
    if (s < NK1) { As = A1; astr = 64; koff = s * 64; }
    else         { As = A2; astr = 128; koff = (s - NK1) * 64; }
#pragma unroll
    for (int q = 0; q < MT / 32; ++q) {
      int row = q * 32 + w * 8 + (lane >> 3);
      gload16(As + (row0 + row) * astr + koff + (lane & 7) * 8,
              lds + q * 4096 + w * 1024);
    }
#pragma unroll
    for (int q = 0; q < NT / 32; ++q) {
      int row = q * 32 + w * 8 + (lane >> 3);
      gload16(WT + (size_t)row * K + s * 64 + (lane & 7) * 8,
              lds + MT * 128 + q * 4096 + w * 1024);
    }
    __syncthreads();
#pragma unroll
    for (int kk = 0; kk < 2; ++kk) {
      bf16x8 a[4], bb[4];
#pragma unroll
      for (int m = 0; m < 4; ++m)
        a[m] = *(const bf16x8*)(lds + (wm * 64 + m * 16 + (lane & 15)) * 128 + kk * 64 + (lane >> 4) * 16);
#pragma unroll
      for (int n = 0; n < 4; ++n)
        bb[n] = *(const bf16x8*)(lds + MT * 128 + (wn * 64 + n * 16 + (lane & 15)) * 128 + kk * 64 + (lane >> 4) * 16);
#pragma unroll
      for (int m = 0; m < 4; ++m)
#pragma unroll
        for (int n = 0; n < 4; ++n)
          acc[m][n] = __builtin_amdgcn_mfma_f32_16x16x32_bf16(a[m], bb[n], acc[m][n], 0, 0, 0);
    }
    __syncthreads();
  }
#pragma unroll
  for (int m = 0; m < 4; ++m) {
    float ax4[4];
    if (RK1) {
      float4 v = *(const float4*)&axv[row0 + wm * 64 + m * 16 + ((lane >> 4) << 2)];
      ax4[0] = v.x; ax4[1] = v.y; ax4[2] = v.z; ax4[3] = v.w;
    }
#pragma unroll
    for (int n = 0; n < 4; ++n) {
      int cp = wn * 64 + n * 16 + (lane & 15);
      bool iz = cp < C;
      int c = iz ? cp : cp - C;
      int rl = wm * 64 + m * 16 + ((lane >> 4) << 2);
      size_t idx = (((size_t)b * C + c) << 10) + n0 + rl;
      u16x4 hv;
      if (!iz) hv = *(const u16x4*)&hT[idx];
      u16x4 pk;
#pragma unroll
      for (int j = 0; j < 4; ++j) {
        float g = acc[m][n][j] + (iz ? bz : br)[c];
        if (RK1) g += ax4[j] * (iz ? wxz : wxr)[c];
        float sg = sigm(g);
        pk[j] = iz ? f2bf(sg) : f2bf(sg * bf2f(hv[j]));
      }
      *(u16x4*)&(iz ? zTo : rhTo)[idx] = pk;
    }
  }
}

// ---------------- fused F: adj@[h1|h2] (192 cols) + zr1(t+1) + zr0(t+2) + AH1 -------
// grid 512 = (b 64) x (panel 8, 128 rows each)
__global__ __launch_bounds__(256) void fused_F(
    const u16* __restrict__ adjB, const u16* __restrict__ h1T, const u16* __restrict__ h2T,
    const u16* __restrict__ WzrT1, const float* __restrict__ bz1, const float* __restrict__ br1,
    const u16* __restrict__ WzrT0, const float* __restrict__ bz0, const float* __restrict__ br0,
    const float* __restrict__ AXt2, const float* __restrict__ wz0x, const float* __restrict__ wr0x,
    u16* __restrict__ AH1, u16* __restrict__ z1T, u16* __restrict__ rh1T,
    u16* __restrict__ z0T, u16* __restrict__ rh0T, int do_zr0) {
  __shared__ __align__(16) char lds[51200];  // stage 40960 -> AN[128][200] 51200
  int tid = threadIdx.x, w = tid >> 6, lane = tid & 63;
  int b = blockIdx.x >> 3, panel = blockIdx.x & 7;
  int row0 = panel * 128;
  int wm = w >> 1, wn = w & 1;
  f32x4 acc[4][6] = {};
  for (int k0 = 0; k0 < 1024; k0 += 64) {
#pragma unroll
    for (int q = 0; q < 4; ++q) {
      int row = q * 32 + w * 8 + (lane >> 3);
      gload16(adjB + (size_t)(row0 + row) * 1024 + k0 + (lane & 7) * 8,
              lds + q * 4096 + w * 1024);
    }
#pragma unroll
    for (int q = 0; q < 6; ++q) {
      int row = q * 32 + w * 8 + (lane >> 3);
      const u16* src = (q < 2) ? (h1T + (((size_t)b * 64 + row) << 10))
                               : (h2T + (((size_t)b * 128 + (row - 64)) << 10));
      gload16(src + k0 + (lane & 7) * 8, lds + 16384 + q * 4096 + w * 1024);
    }
    __syncthreads();
#pragma unroll
    for (int kk = 0; kk < 2; ++kk) {
      bf16x8 a[4], bb[6];
#pragma unroll
      for (int m = 0; m < 4; ++m)
        a[m] = *(const bf16x8*)(lds + (wm * 64 + m * 16 + (lane & 15)) * 128 + kk * 64 + (lane >> 4) * 16);
#pragma unroll
      for (int n = 0; n < 6; ++n)
        bb[n] = *(const bf16x8*)(lds + 16384 + (wn * 96 + n * 16 + (lane & 15)) * 128 + kk * 64 + (lane >> 4) * 16);
#pragma unroll
      for (int m = 0; m < 4; ++m)
#pragma unroll
        for (int n = 0; n < 6; ++n)
          acc[m][n] = __builtin_amdgcn_mfma_f32_16x16x32_bf16(a[m], bb[n], acc[m][n], 0, 0, 0);
    }
    __syncthreads();
  }
  // stage AN[128 rows][192 cols] bf16 (stride 200 u16)
  u16* AN = (u16*)lds;
#pragma unroll
  for (int m = 0; m < 4; ++m)
#pragma unroll
    for (int n = 0; n < 6; ++n) {
      int cl = wn * 96 + n * 16 + (lane & 15);
      int rl = wm * 64 + m * 16 + ((lane >> 4) << 2);
#pragma unroll
      for (int j = 0; j < 4; ++j)
        AN[(rl + j) * 200 + cl] = f2bf(acc[m][n][j]);
    }
  __syncthreads();
  // write AH1 (cols 0..63) for ngate128's x-part
#pragma unroll
  for (int it = 0; it < 4; ++it) {
    int id = tid + it * 256;      // 0..1023
    int row = id >> 3, g = id & 7;
    u16x8 v = *(const u16x8*)&AN[row * 200 + g * 8];
    *(u16x8*)&AH1[(((size_t)b << 10) + row0 + row) * 64 + g * 8] = v;
  }
  // gate1: zr1(t+1), K=192, outs 256 in two halves (z: 0..127, r: 128..255)
#pragma unroll
  for (int hz = 0; hz < 2; ++hz) {
    f32x4 g1[4][4] = {};
#pragma unroll
    for (int kk = 0; kk < 6; ++kk) {
      bf16x8 a[4], bb[4];
#pragma unroll
      for (int m = 0; m < 4; ++m)
        a[m] = *(const bf16x8*)&AN[(wm * 64 + m * 16 + (lane & 15)) * 200 + kk * 32 + (lane >> 4) * 8];
#pragma unroll
      for (int n = 0; n < 4; ++n) {
        int out = hz * 128 + wn * 64 + n * 16 + (lane & 15);
        bb[n] = *(const bf16x8*)&WzrT1[(size_t)out * 192 + kk * 32 + (lane >> 4) * 8];
      }
#pragma unroll
      for (int m = 0; m < 4; ++m)
#pragma unroll
        for (int n = 0; n < 4; ++n)
          g1[m][n] = __builtin_amdgcn_mfma_f32_16x16x32_bf16(a[m], bb[n], g1[m][n], 0, 0, 0);
    }
#pragma unroll
    for (int m = 0; m < 4; ++m)
#pragma unroll
      for (int n = 0; n < 4; ++n) {
        int c = wn * 64 + n * 16 + (lane & 15);
        int grow = wm * 64 + m * 16 + ((lane >> 4) << 2);
        size_t idx = (((size_t)b * 128 + c) << 10) + row0 + grow;
        u16x4 pk;
        if (hz == 0) {
#pragma unroll
          for (int j = 0; j < 4; ++j) pk[j] = f2bf(sigm(g1[m][n][j] + bz1[c]));
          *(u16x4*)&z1T[idx] = pk;
        } else {
          u16x4 hv = *(const u16x4*)&h2T[idx];
#pragma unroll
          for (int j = 0; j < 4; ++j)
            pk[j] = f2bf(sigm(g1[m][n][j] + br1[c]) * bf2f(hv[j]));
          *(u16x4*)&rh1T[idx] = pk;
        }
      }
  }
  // gate0: zr0(t+2), K=64 (AN cols 0..63), outs 128 (z|r), + rank-1 AX
  if (do_zr0) {
    f32x4 g0[4][4] = {};
#pragma unroll
    for (int kk = 0; kk < 2; ++kk) {
      bf16x8 a[4], bb[4];
#pragma unroll
      for (int m = 0; m < 4; ++m)
        a[m] = *(const bf16x8*)&AN[(wm * 64 + m * 16 + (lane & 15)) * 200 + kk * 32 + (lane >> 4) * 8];
#pragma unroll
      for (int n = 0; n < 4; ++n) {
        int out = wn * 64 + n * 16 + (lane & 15);
        bb[n] = *(const bf16x8*)&WzrT0[(size_t)out * 64 + kk * 32 + (lane >> 4) * 8];
      }
#pragma unroll
      for (int m = 0; m < 4; ++m)
#pragma unroll
        for (int n = 0; n < 4; ++n)
          g0[m][n] = __builtin_amdgcn_mfma_f32_16x16x32_bf16(a[m], bb[n], g0[m][n], 0, 0, 0);
    }
#pragma unroll
    for (int m = 0; m < 4; ++m) {
      int grow0 = wm * 64 + m * 16 + ((lane >> 4) << 2);
      float4 axv = *(const float4*)&AXt2[((size_t)b << 10) + row0 + grow0];
      float ax4[4] = {axv.x, axv.y, axv.z, axv.w};
#pragma unroll
      for (int n = 0; n < 4; ++n) {
        int out = wn * 64 + n * 16 + (lane & 15);
        bool iz = out < 64;
        int c = iz ? out : out - 64;
        size_t idx = (((size_t)b * 64 + c) << 10) + row0 + grow0;
        u16x4 hv;
        if (!iz) hv = *(const u16x4*)&h1T[idx];
        u16x4 pk;
#pragma unroll
        for (int j = 0; j < 4; ++j) {
          float g = g0[m][n][j] + (iz ? bz0 : br0)[c] + ax4[j] * (iz ? wz0x : wr0x)[c];
          float sg = sigm(g);
          pk[j] = iz ? f2bf(sg) : f2bf(sg * bf2f(hv[j]));
        }
        *(u16x4*)&(iz ? z0T : rh0T)[idx] = pk;
      }
    }
  }
}

// ---------------- transpose final states: X[b][n*192+c] bf16 ------------------------
__global__ __launch_bounds__(256) void transpose_x(const u16* __restrict__ h1T,
                                                   const u16* __restrict__ h2T,
                                                   u16* __restrict__ X) {
  int b = blockIdx.x;
  int n0 = blockIdx.y * 128;
  __shared__ u16 tile[192][136];
  int tid = threadIdx.x;
#pragma unroll
  for (int i = 0; i < 12; ++i) {
    int id = tid + i * 256;
    int c = id >> 4, g = id & 15;
    u16x8 v;
    if (c < 64) v = *(const u16x8*)&h1T[(((size_t)b << 6) + c) * 1024 + n0 + g * 8];
    else        v = *(const u16x8*)&h2T[(((size_t)b << 7) + (c - 64)) * 1024 + n0 + g * 8];
    *(u16x8*)&tile[c][g * 8] = v;
  }
  __syncthreads();
#pragma unroll
  for (int i = 0; i < 12; ++i) {
    int id = tid + i * 256;
    int n = id / 24, g = id % 24;
    u16x8 v;
#pragma unroll
    for (int j = 0; j < 8; ++j) v[j] = tile[g * 8 + j][n];
    *(u16x8*)&X[(size_t)b * 196608 + (size_t)(n0 + n) * 192 + g * 8] = v;
  }
}

// ---------------- dense head: MFMA, W f32 staged, bf16 via high-16 read -------------
// grid (256 chunks, 2 mats); P[mat][ch][64 b][256 o]
__global__ __launch_bounds__(256) void dense_mfma(const u16* __restrict__ X,
                                                  const float* __restrict__ Wmu,
                                                  const float* __restrict__ Wlv,
                                                  float* __restrict__ P) {
  __shared__ __align__(16) char lds[33280 + 5120];
  float* Ws = (float*)lds;            // [32][260]
  u16* Xs = (u16*)(lds + 33280);      // [64][40]
  int tid = threadIdx.x, w = tid >> 6, lane = tid & 63;
  int ch = blockIdx.x, mat = blockIdx.y;
  const float* Wp = mat ? Wlv : Wmu;
  int kb = ch * DKCHUNK;
  int o4 = (tid & 63) * 4, kk0 = tid >> 6;
  int xrow = tid >> 2, xg = tid & 3;
  f32x4 acc[16] = {};
  float4 wreg[8];
  u16x8 xreg;
  {
    const float* wb = Wp + (size_t)kb * 256;
#pragma unroll
    for (int p = 0; p < 8; ++p)
      wreg[p] = *(const float4*)&wb[(size_t)(kk0 + p * 4) * 256 + o4];
    xreg = *(const u16x8*)&X[(size_t)xrow * 196608 + kb + xg * 8];
  }
  for (int s = 0; s < DKCHUNK / 32; ++s) {
#pragma unroll
    for (int p = 0; p < 8; ++p)
      *(float4*)&Ws[(kk0 + p * 4) * 260 + o4] = wreg[p];
    *(u16x8*)&Xs[xrow * 40 + xg * 8] = xreg;
    __syncthreads();
    if (s + 1 < DKCHUNK / 32) {
      int k1 = kb + (s + 1) * 32;
      const float* wb = Wp + (size_t)k1 * 256;
#pragma unroll
      for (int p = 0; p < 8; ++p)
        wreg[p] = *(const float4*)&wb[(size_t)(kk0 + p * 4) * 256 + o4];
      xreg = *(const u16x8*)&X[(size_t)xrow * 196608 + k1 + xg * 8];
    }
    bf16x8 af = *(const bf16x8*)&Xs[(w * 16 + (lane & 15)) * 40 + (lane >> 4) * 8];
    int kq = (lane >> 4) * 8;
#pragma unroll
    for (int n = 0; n < 16; ++n) {
      int o = n * 16 + (lane & 15);
      unsigned rr[4];
#pragma unroll
      for (int j = 0; j < 4; ++j) {
        unsigned lo = *(const u16*)((const char*)&Ws[(kq + 2 * j) * 260 + o] + 2);
        unsigned hi = *(const u16*)((const char*)&Ws[(kq + 2 * j + 1) * 260 + o] + 2);
        rr[j] = lo | (hi << 16);
      }
      bf16x8 bv = *(const bf16x8*)rr;
      acc[n] = __builtin_amdgcn_mfma_f32_16x16x32_bf16(af, bv, acc[n], 0, 0, 0);
    }
    __syncthreads();
  }
#pragma unroll
  for (int n = 0; n < 16; ++n) {
    int o = n * 16 + (lane & 15);
#pragma unroll
    for (int j = 0; j < 4; ++j) {
      int brow = w * 16 + ((lane >> 4) << 2) + j;
      P[(((size_t)mat * DKCH + ch) * 64 + brow) * 256 + o] = acc[n][j];
    }
  }
}

// ---------------- threefry / eps ----------------------------------------------------
__device__ __forceinline__ unsigned rotl32(unsigned v, int s) {
  return (v << s) | (v >> (32 - s));
}
__device__ void threefry(unsigned k0, unsigned k1, unsigned x0, unsigned x1,
                         unsigned& o0, unsigned& o1) {
  unsigned ks2 = k0 ^ k1 ^ 0x1BD11BDAu;
  unsigned a = x0 + k0, b = x1 + k1;
#define TF_RND(rot) { a += b; b = rotl32(b, rot); b ^= a; }
  TF_RND(13) TF_RND(15) TF_RND(26) TF_RND(6)
  a += k1; b += ks2 + 1u;
  TF_RND(17) TF_RND(29) TF_RND(16) TF_RND(24)
  a += ks2; b += k0 + 2u;
  TF_RND(13) TF_RND(15) TF_RND(26) TF_RND(6)
  a += k0; b += k1 + 3u;
  TF_RND(17) TF_RND(29) TF_RND(16) TF_RND(24)
  a += k1; b += ks2 + 4u;
  TF_RND(13) TF_RND(15) TF_RND(26) TF_RND(6)
  a += ks2; b += k0 + 5u;
#undef TF_RND
  o0 = a; o1 = b;
}

__device__ float u32_to_normal(unsigned bits) {
  unsigned fb = (bits >> 9) | 0x3F800000u;
  float f = __uint_as_float(fb) - 1.0f;
  const float lo = -0.99999994f;
  float u = f * 2.0f + lo;
  u = fmaxf(lo, u);
  float w = -log1pf(-u * u);
  float p;
  if (w < 5.0f) {
    w -= 2.5f;
    p = 2.81022636e-08f;
    p = fmaf(p, w, 3.43273939e-07f);
    p = fmaf(p, w, -3.5233877e-06f);
    p = fmaf(p, w, -4.39150654e-06f);
    p = fmaf(p, w, 0.00021858087f);
    p = fmaf(p, w, -0.00125372503f);
    p = fmaf(p, w, -0.00417768164f);
    p = fmaf(p, w, 0.246640727f);
    p = fmaf(p, w, 1.50140941f);
  } else {
    w = sqrtf(w) - 3.0f;
    p = -0.000200214257f;
    p = fmaf(p, w, 0.000100950558f);
    p = fmaf(p, w, 0.00134934322f);
    p = fmaf(p, w, -0.00367342844f);
    p = fmaf(p, w, 0.00573950773f);
    p = fmaf(p, w, -0.0076224613f);
    p = fmaf(p, w, 0.00943887047f);
    p = fmaf(p, w, 1.00167406f);
    p = fmaf(p, w, 2.83297682f);
  }
  return 1.41421354f * (p * u);
}

__global__ __launch_bounds__(256) void eps_kernel(float* __restrict__ eps) {
  int b = blockIdx.x;
  int o = threadIdx.x;
  unsigned k0, k1;
  threefry(0u, 0u, 0u, 1234u, k0, k1);
  float s = 0.f;
  for (int smp = 0; smp < 50; ++smp) {
    unsigned idx = ((unsigned)smp * 64u + (unsigned)b) * 256u + (unsigned)o;
    unsigned o0, o1, bits;
#if EPS_MODE == 0
    threefry(k0, k1, 0u, idx, o0, o1);
    bits = o0 ^ o1;
#else
    unsigned pp = idx % 409600u, half = idx / 409600u;
    threefry(k0, k1, pp, pp + 409600u, o0, o1);
    bits = half ? o1 : o0;
#endif
    s += u32_to_normal(bits);
  }
  eps[b * 256 + o] = s / 50.0f;
}

// ---------------- final reduce + heads + reparam ------------------------------------
__global__ __launch_bounds__(256) void final_kernel(const float* __restrict__ P,
                                                    const float* __restrict__ bmu,
                                                    const float* __restrict__ blv,
                                                    const float* __restrict__ eps,
                                                    float* __restrict__ out) {
  int b = blockIdx.x, o = threadIdx.x;
  float smu = 0.f, slv = 0.f;
  for (int ch = 0; ch < DKCH; ++ch) {
    smu += P[(((size_t)0 * DKCH + ch) * 64 + b) * 256 + o];
    slv += P[(((size_t)1 * DKCH + ch) * 64 + b) * 256 + o];
  }
  float mu = sigm(smu + bmu[o]);
  float lv = sigm(slv + blv[o]);
  float z = mu + eps[b * 256 + o] * expf(0.5f * lv);
  out[b * 256 + o] = z;
  out[16384 + b * 256 + o] = mu;
  out[32768 + b * 256 + o] = lv;
}

// ------------------------------------------------------------------------------------
extern "C" void kernel_launch(void* const* d_in, const int* in_sizes, int n_in,
                              void* d_out, int out_size, void* d_ws, size_t ws_size,
                              hipStream_t stream) {
  (void)in_sizes; (void)n_in; (void)out_size; (void)ws_size;
  const float* xs  = (const float*)d_in[0];
  const float* adj = (const float*)d_in[1];
  const float* Wz0 = (const float*)d_in[2];  const float* bz0 = (const float*)d_in[3];
  const float* Wr0 = (const float*)d_in[4];  const float* br0 = (const float*)d_in[5];
  const float* Wn0 = (const float*)d_in[6];  const float* bn0 = (const float*)d_in[7];
  const float* Wz1 = (const float*)d_in[8];  const float* bz1 = (const float*)d_in[9];
  const float* Wr1 = (const float*)d_in[10]; const float* br1 = (const float*)d_in[11];
  const float* Wn1 = (const float*)d_in[12]; const float* bn1 = (const float*)d_in[13];
  const float* Wmu = (const float*)d_in[14]; const float* bmu = (const float*)d_in[15];
  const float* Wlv = (const float*)d_in[16]; const float* blv = (const float*)d_in[17];

  float* ws = (float*)d_ws;
  // layout (units of MF f32)
  u16*  adjB  = (u16*)(ws);                  // 0.0  (0.5)
  u16*  xsB   = (u16*)(ws + MF / 2);         // 0.5  (0.5)
  float* AXv  = ws + 1 * MF;                 // 1.0  (1.0)  [t][b][n] f32
  u16*  h1T   = (u16*)(ws + 2 * MF);         // 2.0  (2.0)  [b][64][1024]
  u16*  h2T   = (u16*)(ws + 4 * MF);         // 4.0  (4.0)  [b][128][1024]
  u16*  z0T   = (u16*)(ws + 8 * MF);         // 8.0  (2.0)
  u16*  z1T   = (u16*)(ws + 10 * MF);        // 10.0 (4.0)
  u16*  rh0T  = (u16*)(ws + 14 * MF);        // 14.0 (2.0)
  u16*  rh1T  = (u16*)(ws + 16 * MF);        // 16.0 (4.0)
  u16*  AH1   = (u16*)(ws + 20 * MF);        // 20.0 (2.0)  [b][n][64]
  u16*  WTb   = (u16*)(ws + 26 * MF);        // 26.0 (0.125)
  // post-loop aliases (dead loop buffers):
  u16*  X     = (u16*)(ws + 8 * MF);         // 8.0  (6.0)  [b][196608] bf16
  float* P    = ws + 16 * MF;                // 16.0 (8.4)  dense partials
  float* EPS  = ws + 25 * MF;                // 25.0

  u16* WzrT0 = WTb;
  u16* WnT0  = WTb + 8192;
  u16* WzrT1 = WTb + 12288;
  u16* WnT1  = WTb + 61440;

  // zero initial state h1T,h2T (2..8 MF) and AH1 (20..22 MF)
  hipMemsetAsync(ws + 2 * MF, 0, 6 * MF * sizeof(float), stream);
  hipMemsetAsync(ws + 20 * MF, 0, 2 * MF * sizeof(float), stream);

  cast_bf16<<<1024, 256, 0, stream>>>(adj, adjB, 1 << 20);
  cast_bf16<<<1024, 256, 0, stream>>>(xs, xsB, 1 << 20);
  prep_wt<<<dim3(192, 4), 256, 0, stream>>>(Wz0, Wr0, Wn0, Wz1, Wr1, Wn1,
                                            WzrT0, WnT0, WzrT1, WnT1);

  // AX[t][b][n] = adj @ x_t for all t (cols = (t,b))
  adj_mfma<1, 0, 4><<<dim3(8, 8), 256, 0, stream>>>(adjB, xsB, AXv);

  // ---- prologue: step 0 layer-0 ----
  gate_zr<2, 2, 64, 1, 1, 1><<<512, 256, 0, stream>>>(
      AH1, nullptr, WzrT0, bz0, br0, AXv, Wz0, Wr0, h1T, z0T, rh0T);
  adj_ngate<64, 1, 4><<<dim3(32, 8), 256, 0, stream>>>(
      adjB, rh0T, WnT0, bn0, AXv, Wn0, nullptr, z0T, h1T);

  // ---- pipeline: i = -1..14  (F: adj@[h1(i+1)|h2(i)] + zr1(i+1) + zr0(i+2) + AH1) --
  for (int i = -1; i <= T - 2; ++i) {
    int do0 = (i < T - 2) ? 1 : 0;
    const float* AXt2 = AXv + (size_t)(do0 ? (i + 2) : 0) * 65536;
    fused_F<<<512, 256, 0, stream>>>(adjB, h1T, h2T, WzrT1, bz1, br1,
                                     WzrT0, bz0, br0, AXt2, Wz0, Wr0,
                                     AH1, z1T, rh1T, z0T, rh0T, do0);
    if (i < T - 2)
      combo_ngate<<<768, 256, 0, stream>>>(adjB, rh1T, WnT1, bn1, AH1, z1T, h2T,
                                           rh0T, WnT0, bn0, AXt2, Wn0, z0T, h1T);
    else
      adj_ngate<128, 0, 4><<<dim3(64, 8), 256, 0, stream>>>(
          adjB, rh1T, WnT1, bn1, nullptr, nullptr, AH1, z1T, h2T);
  }

  // dense heads
  transpose_x<<<dim3(64, 8), 256, 0, stream>>>(h1T, h2T, X);
  dense_mfma<<<dim3(DKCH, 2), 256, 0, stream>>>(X, Wmu, Wlv, P);
  eps_kernel<<<64, 256, 0, stream>>>(EPS);
  final_kernel<<<64, 256, 0, stream>>>(P, bmu, blv, EPS, (float*)d_out);
}

// Round 7
// 2995.517 us; speedup vs baseline: 1.1193x; 1.1193x over previous
//
#include <hip/hip_runtime.h>
#include <math.h>

#define EPS_MODE 0

typedef unsigned short u16;
typedef short bf16x8 __attribute__((ext_vector_type(8)));
typedef float f32x4 __attribute__((ext_vector_type(4)));
typedef u16 u16x4 __attribute__((ext_vector_type(4)));
typedef u16 u16x8 __attribute__((ext_vector_type(8)));

static constexpr int T = 16;
static constexpr size_t MF = 1u << 20;
static constexpr int DKCH = 256;                // dense split-K chunks
static constexpr int DKCHUNK = 196608 / DKCH;   // 768

__device__ __forceinline__ u16 f2bf(float f) {
  unsigned u = __float_as_uint(f);
  unsigned r = (u + 0x7fffu + ((u >> 16) & 1u)) >> 16;
  return (u16)r;
}
__device__ __forceinline__ float bf2f(u16 h) {
  return __uint_as_float(((unsigned)h) << 16);
}
__device__ __forceinline__ void gload16(const void* g, void* l) {
  __builtin_amdgcn_global_load_lds(
      (const __attribute__((address_space(1))) void*)g,
      (__attribute__((address_space(3))) void*)l, 16, 0, 0);
}

// ---------------- casts -------------------------------------------------------------
__global__ __launch_bounds__(256) void cast_bf16(const float* __restrict__ in,
                                                 u16* __restrict__ out, int n) {
  int i = (blockIdx.x * 256 + threadIdx.x) * 4;
  if (i < n) {
    float4 v = *reinterpret_cast<const float4*>(&in[i]);
    out[i + 0] = f2bf(v.x); out[i + 1] = f2bf(v.y);
    out[i + 2] = f2bf(v.z); out[i + 3] = f2bf(v.w);
  }
}

// ---------------- W transpose+cast: WT[col][k] --------------------------------------
__global__ __launch_bounds__(256) void prep_wt(const float* __restrict__ Wz0, const float* __restrict__ Wr0,
                                               const float* __restrict__ Wn0, const float* __restrict__ Wz1,
                                               const float* __restrict__ Wr1, const float* __restrict__ Wn1,
                                               u16* __restrict__ WzrT0, u16* __restrict__ WnT0,
                                               u16* __restrict__ WzrT1, u16* __restrict__ WnT1) {
  int seg = blockIdx.y;
  int idx = blockIdx.x * 256 + threadIdx.x;
  if (seg == 0) {        // [128 out][64 k] : z|r, h-part rows 1..64
    if (idx < 128 * 64) {
      int j = idx >> 6, k = idx & 63;
      float v = (j < 64) ? Wz0[(k + 1) * 64 + j] : Wr0[(k + 1) * 64 + (j - 64)];
      WzrT0[idx] = f2bf(v);
    }
  } else if (seg == 1) {  // [64][64]
    if (idx < 64 * 64) {
      int j = idx >> 6, k = idx & 63;
      WnT0[idx] = f2bf(Wn0[(k + 1) * 64 + j]);
    }
  } else if (seg == 2) {  // [256][192]
    if (idx < 256 * 192) {
      int j = idx / 192, k = idx % 192;
      float v = (j < 128) ? Wz1[k * 128 + j] : Wr1[k * 128 + (j - 128)];
      WzrT1[idx] = f2bf(v);
    }
  } else {                // [128][192]
    if (idx < 128 * 192) {
      int j = idx / 192, k = idx % 192;
      WnT1[idx] = f2bf(Wn1[k * 128 + j]);
    }
  }
}

// ---------------- plain adjacency MFMA GEMM -----------------------------------------
// OUT[row][col] = sum_k A[row][k] * BT[col][k]   ((MFR*32-row blocks) x 128-col blocks)
// EPI 0: OUT bf16 [b][n][C]: col=(b<<LOGC)+c
// EPI 1: OUT f32 AX [t][b][n]: col=(t<<6)+b
template <int EPI, int LOGC, int MFR>
__global__ __launch_bounds__(256) void adj_mfma(const u16* __restrict__ A,
                                                const u16* __restrict__ BT,
                                                void* __restrict__ OUT) {
  constexpr int MT = MFR * 32;
  __shared__ __align__(16) char lds[(MFR + 4) * 4096];
  int tid = threadIdx.x;
  int w = tid >> 6, lane = tid & 63;
  int row0 = blockIdx.y * MT, col0 = blockIdx.x * 128;
  int wm = w >> 1, wn = w & 1;
  f32x4 acc[MFR][4] = {};
  for (int k0 = 0; k0 < 1024; k0 += 64) {
#pragma unroll
    for (int q = 0; q < MFR; ++q) {
      int row = q * 32 + w * 8 + (lane >> 3);
      gload16(A + (size_t)(row0 + row) * 1024 + k0 + (lane & 7) * 8,
              lds + q * 4096 + w * 1024);
    }
#pragma unroll
    for (int q = 0; q < 4; ++q) {
      int row = q * 32 + w * 8 + (lane >> 3);
      gload16(BT + (size_t)(col0 + row) * 1024 + k0 + (lane & 7) * 8,
              lds + MFR * 4096 + q * 4096 + w * 1024);
    }
    __syncthreads();
#pragma unroll
    for (int kk = 0; kk < 2; ++kk) {
      bf16x8 a[MFR], bb[4];
#pragma unroll
      for (int m = 0; m < MFR; ++m)
        a[m] = *(const bf16x8*)(lds + (wm * (MFR * 16) + m * 16 + (lane & 15)) * 128 + kk * 64 + (lane >> 4) * 16);
#pragma unroll
      for (int n = 0; n < 4; ++n)
        bb[n] = *(const bf16x8*)(lds + MFR * 4096 + (wn * 64 + n * 16 + (lane & 15)) * 128 + kk * 64 + (lane >> 4) * 16);
#pragma unroll
      for (int m = 0; m < MFR; ++m)
#pragma unroll
        for (int n = 0; n < 4; ++n)
          acc[m][n] = __builtin_amdgcn_mfma_f32_16x16x32_bf16(a[m], bb[n], acc[m][n], 0, 0, 0);
    }
    __syncthreads();
  }
  if (EPI == 1) {
    float* O = (float*)OUT;
#pragma unroll
    for (int m = 0; m < MFR; ++m)
#pragma unroll
      for (int n = 0; n < 4; ++n) {
        int col = col0 + wn * 64 + n * 16 + (lane & 15);
        int t = col >> 6, bbx = col & 63;
        int row = row0 + wm * (MFR * 16) + m * 16 + ((lane >> 4) << 2);
        *(float4*)&O[((size_t)t << 16) + ((size_t)bbx << 10) + row] = *(float4*)&acc[m][n];
      }
  } else {
    u16* O = (u16*)OUT;
    constexpr int C = 1 << LOGC;
#pragma unroll
    for (int m = 0; m < MFR; ++m)
#pragma unroll
      for (int n = 0; n < 4; ++n) {
        int col = col0 + wn * 64 + n * 16 + (lane & 15);
        int bbx = col >> LOGC, c = col & (C - 1);
#pragma unroll
        for (int j = 0; j < 4; ++j) {
          int row = row0 + wm * (MFR * 16) + m * 16 + ((lane >> 4) << 2) + j;
          O[(((size_t)bbx << 10) + row) * C + c] = f2bf(acc[m][n][j]);
        }
      }
  }
}

// ---------------- fused adj@(r*h) + n-gate + GRU update -----------------------------
template <int C, int RK1, int MFR>
__global__ __launch_bounds__(256) void adj_ngate(
    const u16* __restrict__ A, const u16* __restrict__ BT,
    const u16* __restrict__ WnT, const float* __restrict__ bias,
    const float* __restrict__ axv, const float* __restrict__ wx,
    const u16* __restrict__ AH1, const u16* __restrict__ zT,
    u16* __restrict__ hT) {
  constexpr int LOGC = (C == 64) ? 6 : 7;
  constexpr int KW = (C == 64) ? 64 : 192;
  constexpr int KKAN = C / 32;
  constexpr int MT = MFR * 32;
  constexpr int STG = (MFR + 4) * 4096;
  constexpr int ANBYTES = MT * 136 * 2;
  constexpr int LDSZ = STG > ANBYTES ? STG : ANBYTES;
  __shared__ __align__(16) char lds[LDSZ];
  int tid = threadIdx.x;
  int w = tid >> 6, lane = tid & 63;
  int row0 = blockIdx.y * MT, col0 = blockIdx.x * 128;
  int wm = w >> 1, wn = w & 1;
  f32x4 acc[MFR][4] = {};
  for (int k0 = 0; k0 < 1024; k0 += 64) {
#pragma unroll
    for (int q = 0; q < MFR; ++q) {
      int row = q * 32 + w * 8 + (lane >> 3);
      gload16(A + (size_t)(row0 + row) * 1024 + k0 + (lane & 7) * 8,
              lds + q * 4096 + w * 1024);
    }
#pragma unroll
    for (int q = 0; q < 4; ++q) {
      int row = q * 32 + w * 8 + (lane >> 3);
      gload16(BT + (size_t)(col0 + row) * 1024 + k0 + (lane & 7) * 8,
              lds + MFR * 4096 + q * 4096 + w * 1024);
    }
    __syncthreads();
#pragma unroll
    for (int kk = 0; kk < 2; ++kk) {
      bf16x8 a[MFR], bb[4];
#pragma unroll
      for (int m = 0; m < MFR; ++m)
        a[m] = *(const bf16x8*)(lds + (wm * (MFR * 16) + m * 16 + (lane & 15)) * 128 + kk * 64 + (lane >> 4) * 16);
#pragma unroll
      for (int n = 0; n < 4; ++n)
        bb[n] = *(const bf16x8*)(lds + MFR * 4096 + (wn * 64 + n * 16 + (lane & 15)) * 128 + kk * 64 + (lane >> 4) * 16);
#pragma unroll
      for (int m = 0; m < MFR; ++m)
#pragma unroll
        for (int n = 0; n < 4; ++n)
          acc[m][n] = __builtin_amdgcn_mfma_f32_16x16x32_bf16(a[m], bb[n], acc[m][n], 0, 0, 0);
    }
    __syncthreads();
  }
  // acc -> ANt bf16, row stride 136 u16
  u16* ANt = (u16*)lds;
#pragma unroll
  for (int m = 0; m < MFR; ++m)
#pragma unroll
    for (int n = 0; n < 4; ++n) {
      int cl = wn * 64 + n * 16 + (lane & 15);
      int rl = wm * (MFR * 16) + m * 16 + ((lane >> 4) << 2);
#pragma unroll
      for (int j = 0; j < 4; ++j)
        ANt[(rl + j) * 136 + cl] = f2bf(acc[m][n][j]);
    }
  __syncthreads();
  // gate phase
  int wrow = w >> 1, half = w & 1;
  int arow0 = wrow * (MFR * 16);
  int b0 = col0 >> LOGC;
  int out0 = (C == 64) ? 0 : half * 64;
  int kbase = (C == 64) ? half * 64 : 0;
  int b_eff = (C == 64) ? (b0 + half) : b0;
  constexpr int WOFF = (C == 64) ? 0 : 64;
  f32x4 acc2[MFR][4] = {};
#pragma unroll
  for (int kk = 0; kk < KKAN; ++kk) {
    bf16x8 a[MFR], bb[4];
    int ka = kbase + kk * 32 + (lane >> 4) * 8;
#pragma unroll
    for (int m = 0; m < MFR; ++m)
      a[m] = *(const bf16x8*)&ANt[(arow0 + m * 16 + (lane & 15)) * 136 + ka];
#pragma unroll
    for (int n = 0; n < 4; ++n)
      bb[n] = *(const bf16x8*)&WnT[(size_t)(out0 + n * 16 + (lane & 15)) * KW + WOFF + kk * 32 + (lane >> 4) * 8];
#pragma unroll
    for (int m = 0; m < MFR; ++m)
#pragma unroll
      for (int n = 0; n < 4; ++n)
        acc2[m][n] = __builtin_amdgcn_mfma_f32_16x16x32_bf16(a[m], bb[n], acc2[m][n], 0, 0, 0);
  }
  if (C == 128) {  // + AH1 (x) part, K=64
#pragma unroll
    for (int kk = 0; kk < 2; ++kk) {
      bf16x8 a[MFR], bb[4];
#pragma unroll
      for (int m = 0; m < MFR; ++m)
        a[m] = *(const bf16x8*)&AH1[(((size_t)b0 << 10) + row0 + arow0 + m * 16 + (lane & 15)) * 64 + kk * 32 + (lane >> 4) * 8];
#pragma unroll
      for (int n = 0; n < 4; ++n)
        bb[n] = *(const bf16x8*)&WnT[(size_t)(out0 + n * 16 + (lane & 15)) * 192 + kk * 32 + (lane >> 4) * 8];
#pragma unroll
      for (int m = 0; m < MFR; ++m)
#pragma unroll
        for (int n = 0; n < 4; ++n)
          acc2[m][n] = __builtin_amdgcn_mfma_f32_16x16x32_bf16(a[m], bb[n], acc2[m][n], 0, 0, 0);
    }
  }
  // epilogue: n=tanh, h=(1-z)h+z*n, in-place hT
#pragma unroll
  for (int m = 0; m < MFR; ++m) {
    float ax4[4];
    if (RK1) {
      float4 v = *(const float4*)&axv[((size_t)b_eff << 10) + row0 + arow0 + m * 16 + ((lane >> 4) << 2)];
      ax4[0] = v.x; ax4[1] = v.y; ax4[2] = v.z; ax4[3] = v.w;
    }
#pragma unroll
    for (int n = 0; n < 4; ++n) {
      int cp = out0 + n * 16 + (lane & 15);
      int grow = arow0 + m * 16 + ((lane >> 4) << 2);
      size_t idx = (((size_t)b_eff << LOGC) + cp) * 1024 + row0 + grow;
      u16x4 zv = *(const u16x4*)&zT[idx];
      u16x4 hv = *(const u16x4*)&hT[idx];
      u16x4 pk;
#pragma unroll
      for (int j = 0; j < 4; ++j) {
        float g = acc2[m][n][j] + bias[cp];
        if (RK1) g += ax4[j] * wx[cp];
        float nv = tanhf(g);
        float z = bf2f(zv[j]), ho = bf2f(hv[j]);
        pk[j] = f2bf((1.f - z) * ho + z * nv);
      }
      *(u16x4*)&hT[idx] = pk;
    }
  }
}

// ---------------- zr gate GEMM: z/r = sigmoid(.), emits zT and rhT=r*h (bf16, ^T) ---
template <int WM, int WN, int C, int NK1, int NK, int RK1>
__global__ __launch_bounds__(256) void gate_zr(
    const u16* __restrict__ A1, const u16* __restrict__ A2,
    const u16* __restrict__ WT, const float* __restrict__ bz,
    const float* __restrict__ br, const float* __restrict__ axv,
    const float* __restrict__ wxz, const float* __restrict__ wxr,
    const u16* __restrict__ hT, u16* __restrict__ zTo, u16* __restrict__ rhTo) {
  constexpr int MT = WM * 64, NT = WN * 64, K = NK * 64;
  constexpr int NB = 1024 / MT;
  __shared__ __align__(16) char lds[MT * 128 + NT * 128];
  int tid = threadIdx.x;
  int w = tid >> 6, lane = tid & 63;
  int by = blockIdx.x;
  int b = by / NB, n0 = (by % NB) * MT;
  size_t row0 = ((size_t)b << 10) + n0;
  int wm = w / WN, wn = w % WN;
  f32x4 acc[4][4] = {};
  for (int s = 0; s < NK; ++s) {
    const u16* As; int astr, koff;
    if (s < NK1) { As = A1; astr = 64; koff = s * 64; }
    else         { As = A2; astr = 128; koff = (s - NK1) * 64; }
#pragma unroll
    for (int q = 0; q < MT / 32; ++q) {
      int row = q * 32 + w * 8 + (lane >> 3);
      gload16(As + (row0 + row) * astr + koff + (lane & 7) * 8,
              lds + q * 4096 + w * 1024);
    }
#pragma unroll
    for (int q = 0; q < NT / 32; ++q) {
      int row = q * 32 + w * 8 + (lane >> 3);
      gload16(WT + (size_t)row * K + s * 64 + (lane & 7) * 8,
              lds + MT * 128 + q * 4096 + w * 1024);
    }
    __syncthreads();
#pragma unroll
    for (int kk = 0; kk < 2; ++kk) {
      bf16x8 a[4], bb[4];
#pragma unroll
      for (int m = 0; m < 4; ++m)
        a[m] = *(const bf16x8*)(lds + (wm * 64 + m * 16 + (lane & 15)) * 128 + kk * 64 + (lane >> 4) * 16);
#pragma unroll
      for (int n = 0; n < 4; ++n)
        bb[n] = *(const bf16x8*)(lds + MT * 128 + (wn * 64 + n * 16 + (lane & 15)) * 128 + kk * 64 + (lane >> 4) * 16);
#pragma unroll
      for (int m = 0; m < 4; ++m)
#pragma unroll
        for (int n = 0; n < 4; ++n)
          acc[m][n] = __builtin_amdgcn_mfma_f32_16x16x32_bf16(a[m], bb[n], acc[m][n], 0, 0, 0);
    }
    __syncthreads();
  }
#pragma unroll
  for (int m = 0; m < 4; ++m) {
    float ax4[4];
    if (RK1) {
      float4 v = *(const float4*)&axv[row0 + wm * 64 + m * 16 + ((lane >> 4) << 2)];
      ax4[0] = v.x; ax4[1] = v.y; ax4[2] = v.z; ax4[3] = v.w;
    }
#pragma unroll
    for (int n = 0; n < 4; ++n) {
      int cp = wn * 64 + n * 16 + (lane & 15);
      bool iz = cp < C;
      int c = iz ? cp : cp - C;
      int rl = wm * 64 + m * 16 + ((lane >> 4) << 2);
      size_t idx = (((size_t)b * C + c) << 10) + n0 + rl;
      u16x4 hv;
      if (!iz) hv = *(const u16x4*)&hT[idx];
      u16x4 pk;
#pragma unroll
      for (int j = 0; j < 4; ++j) {
        float g = acc[m][n][j] + (iz ? bz : br)[c];
        if (RK1) g += ax4[j] * (iz ? wxz : wxr)[c];
        float sg = 1.f / (1.f + expf(-g));
        pk[j] = iz ? f2bf(sg) : f2bf(sg * bf2f(hv[j]));
      }
      *(u16x4*)&(iz ? zTo : rhTo)[idx] = pk;
    }
  }
}

// ---------------- transpose final states: X[b][n*192+c] bf16 ------------------------
__global__ __launch_bounds__(256) void transpose_x(const u16* __restrict__ h1T,
                                                   const u16* __restrict__ h2T,
                                                   u16* __restrict__ X) {
  int b = blockIdx.x;       // 64
  int n0 = blockIdx.y * 128;  // 8
  __shared__ u16 tile[192][136];
  int tid = threadIdx.x;
#pragma unroll
  for (int i = 0; i < 12; ++i) {
    int id = tid + i * 256;
    int c = id >> 4, g = id & 15;
    u16x8 v;
    if (c < 64) v = *(const u16x8*)&h1T[(((size_t)b << 6) + c) * 1024 + n0 + g * 8];
    else        v = *(const u16x8*)&h2T[(((size_t)b << 7) + (c - 64)) * 1024 + n0 + g * 8];
    *(u16x8*)&tile[c][g * 8] = v;
  }
  __syncthreads();
#pragma unroll
  for (int i = 0; i < 12; ++i) {
    int id = tid + i * 256;
    int n = id / 24, g = id % 24;
    u16x8 v;
#pragma unroll
    for (int j = 0; j < 8; ++j) v[j] = tile[g * 8 + j][n];
    *(u16x8*)&X[(size_t)b * 196608 + (size_t)(n0 + n) * 192 + g * 8] = v;
  }
}

// ---------------- dense head: streaming split-K, 64x128 tile, 4x8 thread tile -------
// P[mat][ch][64 b][256 o] partials; block tile M=64(b) x N=128(o) x K=768
__global__ __launch_bounds__(256) void dense_split2(const u16* __restrict__ X,
                                                    const float* __restrict__ Wmu,
                                                    const float* __restrict__ Wlv,
                                                    float* __restrict__ P) {
  int ot = blockIdx.x, ch = blockIdx.y, mat = blockIdx.z;
  const float* W = mat ? Wlv : Wmu;
  int o0 = ot * 128;
  __shared__ float As[16][68];
  __shared__ float Ws[16][132];
  int tid = threadIdx.x;
  int tx = tid & 15, ty = tid >> 4;             // tx: o-tile (8 wide), ty: b-tile (4)
  int ab = tid >> 2, akq = (tid & 3) * 4;       // X: b=ab, k-sub akq..+3
  int wkk = tid >> 4, wo8 = (tid & 15) * 8;     // W: row wkk, 8 outputs
  int kb = ch * DKCHUNK;
  float acc[4][8] = {};
  u16x4 xa = *(const u16x4*)&X[(size_t)ab * 196608 + kb + akq];
  float4 wv0 = *(const float4*)&W[(size_t)(kb + wkk) * 256 + o0 + wo8];
  float4 wv1 = *(const float4*)&W[(size_t)(kb + wkk) * 256 + o0 + wo8 + 4];
  for (int s = 0; s < DKCHUNK / 16; ++s) {
#pragma unroll
    for (int j = 0; j < 4; ++j) As[akq + j][ab] = bf2f(xa[j]);
    *(float4*)&Ws[wkk][wo8] = wv0;
    *(float4*)&Ws[wkk][wo8 + 4] = wv1;
    __syncthreads();
    if (s + 1 < DKCHUNK / 16) {
      int k0 = kb + (s + 1) * 16;
      xa = *(const u16x4*)&X[(size_t)ab * 196608 + k0 + akq];
      wv0 = *(const float4*)&W[(size_t)(k0 + wkk) * 256 + o0 + wo8];
      wv1 = *(const float4*)&W[(size_t)(k0 + wkk) * 256 + o0 + wo8 + 4];
    }
#pragma unroll
    for (int kk = 0; kk < 16; ++kk) {
      float a[4], bq[8];
      *(float4*)a = *(const float4*)&As[kk][ty * 4];
      *(float4*)bq = *(const float4*)&Ws[kk][tx * 8];
      *(float4*)(bq + 4) = *(const float4*)&Ws[kk][tx * 8 + 4];
#pragma unroll
      for (int i = 0; i < 4; ++i)
#pragma unroll
        for (int j = 0; j < 8; ++j) acc[i][j] += a[i] * bq[j];
    }
    __syncthreads();
  }
#pragma unroll
  for (int i = 0; i < 4; ++i) {
    float4 v0, v1;
    v0.x = acc[i][0]; v0.y = acc[i][1]; v0.z = acc[i][2]; v0.w = acc[i][3];
    v1.x = acc[i][4]; v1.y = acc[i][5]; v1.z = acc[i][6]; v1.w = acc[i][7];
    size_t base = (((size_t)mat * DKCH + ch) * 64 + ty * 4 + i) * 256 + o0 + tx * 8;
    *(float4*)&P[base] = v0;
    *(float4*)&P[base + 4] = v1;
  }
}

// ---------------- threefry / eps ----------------------------------------------------
__device__ __forceinline__ unsigned rotl32(unsigned v, int s) {
  return (v << s) | (v >> (32 - s));
}
__device__ void threefry(unsigned k0, unsigned k1, unsigned x0, unsigned x1,
                         unsigned& o0, unsigned& o1) {
  unsigned ks2 = k0 ^ k1 ^ 0x1BD11BDAu;
  unsigned a = x0 + k0, b = x1 + k1;
#define TF_RND(rot) { a += b; b = rotl32(b, rot); b ^= a; }
  TF_RND(13) TF_RND(15) TF_RND(26) TF_RND(6)
  a += k1; b += ks2 + 1u;
  TF_RND(17) TF_RND(29) TF_RND(16) TF_RND(24)
  a += ks2; b += k0 + 2u;
  TF_RND(13) TF_RND(15) TF_RND(26) TF_RND(6)
  a += k0; b += k1 + 3u;
  TF_RND(17) TF_RND(29) TF_RND(16) TF_RND(24)
  a += k1; b += ks2 + 4u;
  TF_RND(13) TF_RND(15) TF_RND(26) TF_RND(6)
  a += ks2; b += k0 + 5u;
#undef TF_RND
  o0 = a; o1 = b;
}

__device__ float u32_to_normal(unsigned bits) {
  unsigned fb = (bits >> 9) | 0x3F800000u;
  float f = __uint_as_float(fb) - 1.0f;
  const float lo = -0.99999994f;
  float u = f * 2.0f + lo;
  u = fmaxf(lo, u);
  float w = -log1pf(-u * u);
  float p;
  if (w < 5.0f) {
    w -= 2.5f;
    p = 2.81022636e-08f;
    p = fmaf(p, w, 3.43273939e-07f);
    p = fmaf(p, w, -3.5233877e-06f);
    p = fmaf(p, w, -4.39150654e-06f);
    p = fmaf(p, w, 0.00021858087f);
    p = fmaf(p, w, -0.00125372503f);
    p = fmaf(p, w, -0.00417768164f);
    p = fmaf(p, w, 0.246640727f);
    p = fmaf(p, w, 1.50140941f);
  } else {
    w = sqrtf(w) - 3.0f;
    p = -0.000200214257f;
    p = fmaf(p, w, 0.000100950558f);
    p = fmaf(p, w, 0.00134934322f);
    p = fmaf(p, w, -0.00367342844f);
    p = fmaf(p, w, 0.00573950773f);
    p = fmaf(p, w, -0.0076224613f);
    p = fmaf(p, w, 0.00943887047f);
    p = fmaf(p, w, 1.00167406f);
    p = fmaf(p, w, 2.83297682f);
  }
  return 1.41421354f * (p * u);
}

__global__ __launch_bounds__(256) void eps_kernel(float* __restrict__ eps) {
  int b = blockIdx.x;
  int o = threadIdx.x;
  unsigned k0, k1;
  threefry(0u, 0u, 0u, 1234u, k0, k1);
  float s = 0.f;
  for (int smp = 0; smp < 50; ++smp) {
    unsigned idx = ((unsigned)smp * 64u + (unsigned)b) * 256u + (unsigned)o;
    unsigned o0, o1, bits;
#if EPS_MODE == 0
    threefry(k0, k1, 0u, idx, o0, o1);
    bits = o0 ^ o1;
#else
    unsigned pp = idx % 409600u, half = idx / 409600u;
    threefry(k0, k1, pp, pp + 409600u, o0, o1);
    bits = half ? o1 : o0;
#endif
    s += u32_to_normal(bits);
  }
  eps[b * 256 + o] = s / 50.0f;
}

// ---------------- final reduce + heads + reparam ------------------------------------
__global__ __launch_bounds__(256) void final_kernel(const float* __restrict__ P,
                                                    const float* __restrict__ bmu,
                                                    const float* __restrict__ blv,
                                                    const float* __restrict__ eps,
                                                    float* __restrict__ out) {
  int b = blockIdx.x, o = threadIdx.x;
  float smu = 0.f, slv = 0.f;
  for (int ch = 0; ch < DKCH; ++ch) {
    smu += P[(((size_t)0 * DKCH + ch) * 64 + b) * 256 + o];
    slv += P[(((size_t)1 * DKCH + ch) * 64 + b) * 256 + o];
  }
  float mu = 1.f / (1.f + expf(-(smu + bmu[o])));
  float lv = 1.f / (1.f + expf(-(slv + blv[o])));
  float z = mu + eps[b * 256 + o] * expf(0.5f * lv);
  out[b * 256 + o] = z;
  out[16384 + b * 256 + o] = mu;
  out[32768 + b * 256 + o] = lv;
}

// ------------------------------------------------------------------------------------
extern "C" void kernel_launch(void* const* d_in, const int* in_sizes, int n_in,
                              void* d_out, int out_size, void* d_ws, size_t ws_size,
                              hipStream_t stream) {
  (void)in_sizes; (void)n_in; (void)out_size; (void)ws_size;
  const float* xs  = (const float*)d_in[0];
  const float* adj = (const float*)d_in[1];
  const float* Wz0 = (const float*)d_in[2];  const float* bz0 = (const float*)d_in[3];
  const float* Wr0 = (const float*)d_in[4];  const float* br0 = (const float*)d_in[5];
  const float* Wn0 = (const float*)d_in[6];  const float* bn0 = (const float*)d_in[7];
  const float* Wz1 = (const float*)d_in[8];  const float* bz1 = (const float*)d_in[9];
  const float* Wr1 = (const float*)d_in[10]; const float* br1 = (const float*)d_in[11];
  const float* Wn1 = (const float*)d_in[12]; const float* bn1 = (const float*)d_in[13];
  const float* Wmu = (const float*)d_in[14]; const float* bmu = (const float*)d_in[15];
  const float* Wlv = (const float*)d_in[16]; const float* blv = (const float*)d_in[17];

  float* ws = (float*)d_ws;
  // layout (units of MF f32)
  u16*  adjB  = (u16*)(ws);                  // 0.0  (0.5)
  u16*  xsB   = (u16*)(ws + MF / 2);         // 0.5  (0.5)
  float* AXv  = ws + 1 * MF;                 // 1.0  (1.0)  [t][b][n] f32
  u16*  h1T   = (u16*)(ws + 2 * MF);         // 2.0  (2.0)  [b][64][1024]
  u16*  h2T   = (u16*)(ws + 4 * MF);         // 4.0  (4.0)  [b][128][1024]
  u16*  z0T   = (u16*)(ws + 8 * MF);         // 8.0  (2.0)
  u16*  z1T   = (u16*)(ws + 10 * MF);        // 10.0 (4.0)
  u16*  rh0T  = (u16*)(ws + 14 * MF);        // 14.0 (2.0)
  u16*  rh1T  = (u16*)(ws + 16 * MF);        // 16.0 (4.0)
  u16*  AH1   = (u16*)(ws + 20 * MF);        // 20.0 (2.0)  [b][n][64]
  u16*  AH2   = (u16*)(ws + 22 * MF);        // 22.0 (4.0)  [b][n][128]
  u16*  WTb   = (u16*)(ws + 26 * MF);        // 26.0 (0.125)
  // post-loop aliases (dead loop buffers):
  u16*  X     = (u16*)(ws + 8 * MF);         // 8.0  (6.0)  [b][196608] bf16
  float* P    = ws + 16 * MF;                // 16.0 (8.0)  dense partials
  float* EPS  = ws + 24 * MF;                // 24.0

  u16* WzrT0 = WTb;
  u16* WnT0  = WTb + 8192;
  u16* WzrT1 = WTb + 12288;
  u16* WnT1  = WTb + 61440;

  // zero initial state h1T,h2T (2..8 MF) and AH1,AH2 (20..26 MF)
  hipMemsetAsync(ws + 2 * MF, 0, 6 * MF * sizeof(float), stream);
  hipMemsetAsync(ws + 20 * MF, 0, 6 * MF * sizeof(float), stream);

  cast_bf16<<<1024, 256, 0, stream>>>(adj, adjB, 1 << 20);
  cast_bf16<<<1024, 256, 0, stream>>>(xs, xsB, 1 << 20);
  prep_wt<<<dim3(192, 4), 256, 0, stream>>>(Wz0, Wr0, Wn0, Wz1, Wr1, Wn1,
                                            WzrT0, WnT0, WzrT1, WnT1);

  // AX[t][b][n] = adj @ x_t for all t (cols = (t,b))
  adj_mfma<1, 0, 4><<<dim3(8, 8), 256, 0, stream>>>(adjB, xsB, AXv);

  for (int t = 0; t < T; ++t) {
    const float* AXt = AXv + (size_t)t * 65536;
    // ---- layer 0 (C=64) ----
    gate_zr<2, 2, 64, 1, 1, 1><<<512, 256, 0, stream>>>(
        AH1, nullptr, WzrT0, bz0, br0, AXt, Wz0, Wr0, h1T, z0T, rh0T);
    adj_ngate<64, 1, 2><<<dim3(32, 16), 256, 0, stream>>>(
        adjB, rh0T, WnT0, bn0, AXt, Wn0, nullptr, z0T, h1T);
    adj_mfma<0, 6, 2><<<dim3(32, 16), 256, 0, stream>>>(adjB, h1T, AH1);
    // ---- layer 1 (C=128) ----
    gate_zr<1, 4, 128, 1, 3, 0><<<1024, 256, 0, stream>>>(
        AH1, AH2, WzrT1, bz1, br1, nullptr, nullptr, nullptr, h2T, z1T, rh1T);
    adj_ngate<128, 0, 4><<<dim3(64, 8), 256, 0, stream>>>(
        adjB, rh1T, WnT1, bn1, nullptr, nullptr, AH1, z1T, h2T);
    if (t + 1 < T)
      adj_mfma<0, 7, 4><<<dim3(64, 8), 256, 0, stream>>>(adjB, h2T, AH2);
  }

  // dense heads: transpose states to natural-k order, then stream W
  transpose_x<<<dim3(64, 8), 256, 0, stream>>>(h1T, h2T, X);
  dense_split2<<<dim3(2, DKCH, 2), 256, 0, stream>>>(X, Wmu, Wlv, P);
  eps_kernel<<<64, 256, 0, stream>>>(EPS);
  final_kernel<<<64, 256, 0, stream>>>(P, bmu, blv, EPS, (float*)d_out);
}